// Round 1
// baseline (401.416 us; speedup 1.0000x reference)
//
#include <hip/hip_runtime.h>

#define U 4096
#define S 8192
#define D 32
#define NUM_REGIONS 128
#define GA 0.1f

#define TU 32      // users per block
#define TI 512     // items per block (2 per thread)
#define THREADS 256

// ---------------- region loss helpers ----------------

__global__ void region_accum_kernel(const float* __restrict__ user_emb,
                                    const int* __restrict__ region_index,
                                    float* __restrict__ sums,      // [R, D]
                                    float* __restrict__ counts) {  // [R]
    int idx = blockIdx.x * blockDim.x + threadIdx.x;  // over U*D
    if (idx >= U * D) return;
    int u = idx >> 5;        // /D
    int d = idx & (D - 1);   // %D
    int r = region_index[u];
    atomicAdd(&sums[r * D + d], user_emb[idx]);
    if (d == 0) atomicAdd(&counts[r], 1.0f);
}

__global__ void region_loss_kernel(const float* __restrict__ user_emb,
                                   const int* __restrict__ region_index,
                                   const float* __restrict__ sums,
                                   const float* __restrict__ counts,
                                   float* __restrict__ rl_accum) {
    int idx = blockIdx.x * blockDim.x + threadIdx.x;
    float v = 0.0f;
    if (idx < U * D) {
        int u = idx >> 5;
        int d = idx & (D - 1);
        int r = region_index[u];
        float cnt = counts[r];
        if (cnt > 1.0f) {
            float e = user_emb[idx];
            float loo = (sums[r * D + d] - e) / fmaxf(cnt - 1.0f, 1.0f);
            v = fabsf(e - loo);
        }
    }
    // wave64 reduce
    #pragma unroll
    for (int off = 32; off > 0; off >>= 1) v += __shfl_down(v, off, 64);
    __shared__ float wp[THREADS / 64];
    int lane = threadIdx.x & 63, wid = threadIdx.x >> 6;
    if (lane == 0) wp[wid] = v;
    __syncthreads();
    if (threadIdx.x == 0) {
        float t = 0.0f;
        #pragma unroll
        for (int i = 0; i < THREADS / 64; i++) t += wp[i];
        atomicAdd(rl_accum, t);
    }
}

// ---------------- main masked-MSE kernel ----------------

__global__ __launch_bounds__(THREADS) void mse_kernel(
    const float* __restrict__ user_emb,
    const float* __restrict__ item_emb,
    const int* __restrict__ train_mask,
    const float* __restrict__ true_qos,
    const float* __restrict__ us_lossweight,
    float* __restrict__ loss_accum) {
    __shared__ float uemb[TU][D];  // 4 KB user tile

    const int ub = blockIdx.x * TU;
    const int sb = blockIdx.y * TI;

    // cooperative load of user tile: TU*D = 1024 floats = 256 float4
    {
        const float4* src = (const float4*)(user_emb + (size_t)ub * D);
        ((float4*)&uemb[0][0])[threadIdx.x] = src[threadIdx.x];
    }
    __syncthreads();

    const int s0 = sb + 2 * threadIdx.x;  // this thread's 2 items

    // item rows into registers (L2-resident: item_emb is 1 MiB total)
    float4 ir0[8], ir1[8];
    {
        const float4* ip0 = (const float4*)(item_emb + (size_t)s0 * D);
        const float4* ip1 = (const float4*)(item_emb + (size_t)(s0 + 1) * D);
        #pragma unroll
        for (int k = 0; k < 8; k++) { ir0[k] = ip0[k]; ir1[k] = ip1[k]; }
    }

    float acc = 0.0f;
    #pragma unroll 1
    for (int uu = 0; uu < TU; uu++) {
        const size_t base = (size_t)(ub + uu) * S + s0;
        // coalesced streaming loads: lanes cover consecutive items
        int2   m = *(const int2*)(train_mask + base);
        float2 q = *(const float2*)(true_qos + base);
        float2 w = *(const float2*)(us_lossweight + base);

        float d0 = 0.0f, d1 = 0.0f;
        const float4* ur = (const float4*)&uemb[uu][0];  // broadcast LDS reads
        #pragma unroll
        for (int k = 0; k < 8; k++) {
            float4 uv = ur[k];
            d0 += uv.x * ir0[k].x + uv.y * ir0[k].y + uv.z * ir0[k].z + uv.w * ir0[k].w;
            d1 += uv.x * ir1[k].x + uv.y * ir1[k].y + uv.z * ir1[k].z + uv.w * ir1[k].w;
        }
        float p0 = d0 * (float)m.x;
        float p1 = d1 * (float)m.y;
        float e0 = p0 - q.x;
        float e1 = p1 - q.y;
        acc += w.x * e0 * e0 + w.y * e1 * e1;
    }

    // wave64 reduce + one atomic per block
    #pragma unroll
    for (int off = 32; off > 0; off >>= 1) acc += __shfl_down(acc, off, 64);
    __shared__ float wp[THREADS / 64];
    int lane = threadIdx.x & 63, wid = threadIdx.x >> 6;
    if (lane == 0) wp[wid] = acc;
    __syncthreads();
    if (threadIdx.x == 0) {
        float t = 0.0f;
        #pragma unroll
        for (int i = 0; i < THREADS / 64; i++) t += wp[i];
        atomicAdd(loss_accum, t);
    }
}

__global__ void finalize_kernel(const float* __restrict__ loss_acc,
                                const float* __restrict__ rl_acc,
                                float* __restrict__ out) {
    out[0] = loss_acc[0] + GA * rl_acc[0];
}

extern "C" void kernel_launch(void* const* d_in, const int* in_sizes, int n_in,
                              void* d_out, int out_size, void* d_ws, size_t ws_size,
                              hipStream_t stream) {
    const float* user_emb      = (const float*)d_in[0];
    const float* item_emb      = (const float*)d_in[1];
    const int*   train_mask    = (const int*)d_in[2];
    const float* true_qos      = (const float*)d_in[3];
    const float* us_lossweight = (const float*)d_in[4];
    const int*   region_index  = (const int*)d_in[5];
    float* out = (float*)d_out;

    float* ws       = (float*)d_ws;
    float* sums     = ws;                          // R*D
    float* counts   = sums + NUM_REGIONS * D;      // R
    float* loss_acc = counts + NUM_REGIONS;        // 1
    float* rl_acc   = loss_acc + 1;                // 1
    size_t zero_bytes = (size_t)(NUM_REGIONS * D + NUM_REGIONS + 2) * sizeof(float);
    hipMemsetAsync(d_ws, 0, zero_bytes, stream);

    region_accum_kernel<<<(U * D + 255) / 256, 256, 0, stream>>>(
        user_emb, region_index, sums, counts);
    region_loss_kernel<<<(U * D + 255) / 256, 256, 0, stream>>>(
        user_emb, region_index, sums, counts, rl_acc);

    dim3 grid(U / TU, S / TI);
    mse_kernel<<<grid, THREADS, 0, stream>>>(
        user_emb, item_emb, train_mask, true_qos, us_lossweight, loss_acc);

    finalize_kernel<<<1, 1, 0, stream>>>(loss_acc, rl_acc, out);
}